// Round 1
// baseline (419.702 us; speedup 1.0000x reference)
//
#include <hip/hip_runtime.h>

#define O_DIM   1024
#define C_DIM   512
#define HW      784
#define B_DIM   32
#define T_POS   8      // spatial positions per workgroup
#define NTILES  (HW / T_POS)   // 98
#define NTHREADS 256

__device__ __forceinline__ float2 cmul(float2 a, float2 b) {
    return make_float2(a.x * b.x - a.y * b.y, a.x * b.y + a.y * b.x);
}

// 32-point in-register DIF FFT. SGN=-1 forward, +1 inverse (no scaling).
// Input natural order; output y[i] = X[rev5(i)].
template<int SGN>
__device__ __forceinline__ void fft32(float2 y[32]) {
    static constexpr float C32[16] = {
        1.f, 0.98078528f, 0.92387953f, 0.83146961f,
        0.70710678f, 0.55557023f, 0.38268343f, 0.19509032f,
        0.f, -0.19509032f, -0.38268343f, -0.55557023f,
        -0.70710678f, -0.83146961f, -0.92387953f, -0.98078528f};
    static constexpr float S32[16] = {
        0.f, 0.19509032f, 0.38268343f, 0.55557023f,
        0.70710678f, 0.83146961f, 0.92387953f, 0.98078528f,
        1.f, 0.98078528f, 0.92387953f, 0.83146961f,
        0.70710678f, 0.55557023f, 0.38268343f, 0.19509032f};
#pragma unroll
    for (int s = 0; s < 5; ++s) {
        const int L = 32 >> s;
        const int h = 16 >> s;
#pragma unroll
        for (int u = 0; u < 16; ++u) {
            const int blk = u >> (4 - s);
            const int t   = u & (h - 1);
            const int i   = blk * L + t;
            const int m   = t << s;            // twiddle index: W32^m
            float2 a = y[i], b = y[i + h];
            y[i] = make_float2(a.x + b.x, a.y + b.y);
            float2 d = make_float2(a.x - b.x, a.y - b.y);
            if (m == 0) {
                y[i + h] = d;
            } else if (m == 8) {
                y[i + h] = (SGN < 0) ? make_float2(d.y, -d.x)
                                     : make_float2(-d.y, d.x);
            } else {
                float2 w = make_float2(C32[m], (SGN < 0) ? -S32[m] : S32[m]);
                y[i + h] = cmul(d, w);
            }
        }
    }
}

// Four-step 1024-pt FFT over zg[0..1023] (one position, 32 threads p=0..31).
// Natural-order in, natural-order out. Unnormalized DFT with sign SGN.
template<int SGN>
__device__ __forceinline__ void four_step(float2* zg, int p) {
    static constexpr int REV5[32] = {
        0,16,8,24,4,20,12,28,2,18,10,26,6,22,14,30,
        1,17,9,25,5,21,13,29,3,19,11,27,7,23,15,31};
    float2 y[32];
    // step A: read column p (z[p + 32*n2])
#pragma unroll
    for (int n2 = 0; n2 < 32; ++n2)
        y[n2] = zg[p + 32 * n2];
    __syncthreads();
    fft32<SGN>(y);                 // A[p][k2] at y[rev5(k2)]
    // step B/C: multiply by W1024^(p*k2), write transposed+swizzled
    float sv, cv;
    __sincosf((float)SGN * 6.283185307179586f * (float)p * (1.f / 1024.f), &sv, &cv);
    const float2 stw = make_float2(cv, sv);
    float2 w = make_float2(1.f, 0.f);
#pragma unroll
    for (int k2 = 0; k2 < 32; ++k2) {
        float2 val = y[REV5[k2]];
        if (k2 > 0) val = cmul(val, w);
        zg[k2 * 32 + ((p + k2) & 31)] = val;   // row k2, swizzled col p
        w = cmul(w, stw);
    }
    __syncthreads();
    // step D: read swizzled row p (all n1)
#pragma unroll
    for (int n1 = 0; n1 < 32; ++n1)
        y[n1] = zg[p * 32 + ((n1 + p) & 31)];
    __syncthreads();
    fft32<SGN>(y);                 // B[p][k1] at y[rev5(k1)]
    // step E: natural-order write: X[p + 32*k1]
#pragma unroll
    for (int k1 = 0; k1 < 32; ++k1)
        zg[p + 32 * k1] = y[REV5[k1]];
    __syncthreads();
}

__global__ void extract_sketch(const float* __restrict__ sk1,
                               const float* __restrict__ sk2,
                               int* __restrict__ h, float* __restrict__ s) {
    int t = blockIdx.x * blockDim.x + threadIdx.x;   // 0..1023
    if (t >= 2 * C_DIM) return;
    const float* sk = (t < C_DIM) ? sk1 : sk2;
    int c = t & (C_DIM - 1);
    int hv = 0; float svv = 0.f;
    for (int o = 0; o < O_DIM; ++o) {
        float v = sk[o * C_DIM + c];
        if (v != 0.f) { hv = o; svv = v; }
    }
    h[t] = hv;
    s[t] = svv;
}

__global__ __launch_bounds__(NTHREADS)
void cbp_main(const float* __restrict__ x1, const float* __restrict__ x2,
              const int* __restrict__ h1, const int* __restrict__ h2,
              const float* __restrict__ s1, const float* __restrict__ s2,
              float* __restrict__ out) {
    __shared__ float2 Z[T_POS][O_DIM];   // 64 KB
    const int tid  = threadIdx.x;
    const int b    = blockIdx.x / NTILES;
    const int tile = blockIdx.x % NTILES;
    const int n0   = tile * T_POS;

    // zero LDS
    float2* zf = &Z[0][0];
#pragma unroll
    for (int i = 0; i < (T_POS * O_DIM) / NTHREADS; ++i)
        zf[tid + NTHREADS * i] = make_float2(0.f, 0.f);
    __syncthreads();

    // scatter: z[j][h1[c]].re += s1[c]*x1, z[j][h2[c]].im += s2[c]*x2
    {
        const int cpart = tid & 31;
        const int j     = tid >> 5;            // 0..7
        const int xbase = b * (C_DIM * HW) + n0 + j;
#pragma unroll 4
        for (int rep = 0; rep < C_DIM / 32; ++rep) {
            const int c  = cpart + (rep << 5);
            const float v1 = x1[xbase + c * HW];
            const float v2 = x2[xbase + c * HW];
            const int   b1 = h1[c], b2 = h2[c];
            const float w1 = s1[c], w2 = s2[c];
            atomicAdd(&Z[j][b1].x, w1 * v1);
            atomicAdd(&Z[j][b2].y, w2 * v2);
        }
    }
    __syncthreads();

    const int g = tid >> 5;       // position group 0..7
    const int p = tid & 31;       // lane-in-position
    float2* zg = &Z[g][0];

    // forward FFT of z = p1 + i*p2
    four_step<-1>(zg, p);

    // Hermitian unpack + pointwise product (natural order), in-place
#pragma unroll
    for (int m = 0; m < 16; ++m) {
        const int k = p + (m << 5);
        if (k == 0) {
            float2 z0 = zg[0];
            float2 z5 = zg[512];
            zg[0]   = make_float2(z0.x * z0.y, 0.f);
            zg[512] = make_float2(z5.x * z5.y, 0.f);
        } else {
            float2 za = zg[k];
            float2 zb = zg[1024 - k];
            float2 F1 = make_float2(0.5f * (za.x + zb.x), 0.5f * (za.y - zb.y));
            float2 F2 = make_float2(0.5f * (za.y + zb.y), -0.5f * (za.x - zb.x));
            float2 G  = cmul(F1, F2);
            zg[k]        = G;
            zg[1024 - k] = make_float2(G.x, -G.y);
        }
    }
    __syncthreads();

    // inverse FFT (unnormalized); real part / 1024 is the conv result
    four_step<1>(zg, p);

    // store: out[b, o, n0+j] — 8 consecutive spatial floats per o
    {
        const int j  = tid & 7;
        const int ob = tid >> 3;              // 0..31
        const int obase = b * (O_DIM * HW) + n0 + j;
#pragma unroll 4
        for (int rep = 0; rep < O_DIM / 32; ++rep) {
            const int o = ob + (rep << 5);
            out[obase + o * HW] = Z[j][o].x * (1.f / 1024.f);
        }
    }
}

extern "C" void kernel_launch(void* const* d_in, const int* in_sizes, int n_in,
                              void* d_out, int out_size, void* d_ws, size_t ws_size,
                              hipStream_t stream) {
    const float* x1  = (const float*)d_in[0];
    const float* x2  = (const float*)d_in[1];
    const float* sk1 = (const float*)d_in[2];
    const float* sk2 = (const float*)d_in[3];
    float* out = (float*)d_out;

    int*   h = (int*)d_ws;                         // [0..511]=h1, [512..1023]=h2
    float* s = (float*)((char*)d_ws + 4096);       // [0..511]=s1, [512..1023]=s2

    hipLaunchKernelGGL(extract_sketch, dim3(4), dim3(256), 0, stream, sk1, sk2, h, s);
    hipLaunchKernelGGL(cbp_main, dim3(B_DIM * NTILES), dim3(NTHREADS), 0, stream,
                       x1, x2, h, h + C_DIM, s, s + C_DIM, out);
}

// Round 2
// 361.840 us; speedup vs baseline: 1.1599x; 1.1599x over previous
//
#include <hip/hip_runtime.h>

#define O_DIM   1024
#define C_DIM   512
#define HW      784
#define B_DIM   32
#define T_POS   4                // spatial positions per workgroup
#define NTILES  (HW / T_POS)     // 196
#define NTHREADS 128

__device__ __forceinline__ float2 cmul(float2 a, float2 b) {
    return make_float2(a.x * b.x - a.y * b.y, a.x * b.y + a.y * b.x);
}

// 32-point in-register DIF FFT. SGN=-1 forward, +1 inverse (no scaling).
// Input natural order; output y[i] = X[rev5(i)].
template<int SGN>
__device__ __forceinline__ void fft32(float2 y[32]) {
    static constexpr float C32[16] = {
        1.f, 0.98078528f, 0.92387953f, 0.83146961f,
        0.70710678f, 0.55557023f, 0.38268343f, 0.19509032f,
        0.f, -0.19509032f, -0.38268343f, -0.55557023f,
        -0.70710678f, -0.83146961f, -0.92387953f, -0.98078528f};
    static constexpr float S32[16] = {
        0.f, 0.19509032f, 0.38268343f, 0.55557023f,
        0.70710678f, 0.83146961f, 0.92387953f, 0.98078528f,
        1.f, 0.98078528f, 0.92387953f, 0.83146961f,
        0.70710678f, 0.55557023f, 0.38268343f, 0.19509032f};
#pragma unroll
    for (int s = 0; s < 5; ++s) {
        const int L = 32 >> s;
        const int h = 16 >> s;
#pragma unroll
        for (int u = 0; u < 16; ++u) {
            const int blk = u >> (4 - s);
            const int t   = u & (h - 1);
            const int i   = blk * L + t;
            const int m   = t << s;            // twiddle index: W32^m
            float2 a = y[i], b = y[i + h];
            y[i] = make_float2(a.x + b.x, a.y + b.y);
            float2 d = make_float2(a.x - b.x, a.y - b.y);
            if (m == 0) {
                y[i + h] = d;
            } else if (m == 8) {
                y[i + h] = (SGN < 0) ? make_float2(d.y, -d.x)
                                     : make_float2(-d.y, d.x);
            } else {
                float2 w = make_float2(C32[m], (SGN < 0) ? -S32[m] : S32[m]);
                y[i + h] = cmul(d, w);
            }
        }
    }
}

// Four-step 1024-pt FFT over zg[0..1023]. One 32-lane group (inside ONE wave)
// owns this row, so same-wave DS ordering makes barriers unnecessary —
// wave_barrier() only stops compiler reordering (no HW cost).
template<int SGN>
__device__ __forceinline__ void four_step(float2* zg, int p) {
    static constexpr int REV5[32] = {
        0,16,8,24,4,20,12,28,2,18,10,26,6,22,14,30,
        1,17,9,25,5,21,13,29,3,19,11,27,7,23,15,31};
    float2 y[32];
#pragma unroll
    for (int n2 = 0; n2 < 32; ++n2)
        y[n2] = zg[p + 32 * n2];
    __builtin_amdgcn_wave_barrier();
    fft32<SGN>(y);                 // A[p][k2] at y[rev5(k2)]
    float sv, cv;
    __sincosf((float)SGN * 6.283185307179586f * (float)p * (1.f / 1024.f), &sv, &cv);
    const float2 stw = make_float2(cv, sv);
    float2 w = make_float2(1.f, 0.f);
#pragma unroll
    for (int k2 = 0; k2 < 32; ++k2) {
        float2 val = y[REV5[k2]];
        if (k2 > 0) val = cmul(val, w);
        zg[k2 * 32 + ((p + k2) & 31)] = val;   // row k2, swizzled col p
        w = cmul(w, stw);
    }
    __builtin_amdgcn_wave_barrier();
#pragma unroll
    for (int n1 = 0; n1 < 32; ++n1)
        y[n1] = zg[p * 32 + ((n1 + p) & 31)];
    __builtin_amdgcn_wave_barrier();
    fft32<SGN>(y);                 // B[p][k1] at y[rev5(k1)]
#pragma unroll
    for (int k1 = 0; k1 < 32; ++k1)
        zg[p + 32 * k1] = y[REV5[k1]];
    __builtin_amdgcn_wave_barrier();
}

// One block per output row o; lanes sweep c coalesced. Each column c has
// exactly one nonzero across o, so the winning thread writes without races.
__global__ void extract_sketch(const float* __restrict__ sk1,
                               const float* __restrict__ sk2,
                               int* __restrict__ h, float* __restrict__ s) {
    const int o = blockIdx.x;                 // 0..1023
    for (int c = threadIdx.x; c < C_DIM; c += blockDim.x) {
        float v1 = sk1[o * C_DIM + c];
        if (v1 != 0.f) { h[c] = o; s[c] = v1; }
        float v2 = sk2[o * C_DIM + c];
        if (v2 != 0.f) { h[C_DIM + c] = o; s[C_DIM + c] = v2; }
    }
}

__global__ __launch_bounds__(NTHREADS)
void cbp_main(const float* __restrict__ x1, const float* __restrict__ x2,
              const int* __restrict__ h1, const int* __restrict__ h2,
              const float* __restrict__ s1, const float* __restrict__ s2,
              float* __restrict__ out) {
    __shared__ float2 Z[T_POS][O_DIM];   // 32 KB -> 5 wg/CU
    const int tid  = threadIdx.x;
    const int b    = blockIdx.x / NTILES;
    const int tile = blockIdx.x % NTILES;
    const int n0   = tile * T_POS;

    // ---- prefetch x-tile + sketch into registers (float4 rows, aligned) ----
    float4 v1[4], v2[4];
    int    b1[4], b2[4];
    float  w1[4], w2[4];
    const int xoff = b * (C_DIM * HW) + n0;
#pragma unroll
    for (int r = 0; r < 4; ++r) {
        const int c = tid + NTHREADS * r;
        v1[r] = *reinterpret_cast<const float4*>(x1 + xoff + c * HW);
        v2[r] = *reinterpret_cast<const float4*>(x2 + xoff + c * HW);
        b1[r] = h1[c];  b2[r] = h2[c];
        w1[r] = s1[c];  w2[r] = s2[c];
    }

    // ---- zero LDS (load latency hides behind this) ----
    float2* zf = &Z[0][0];
#pragma unroll
    for (int i = 0; i < (T_POS * O_DIM) / NTHREADS; ++i)
        zf[tid + NTHREADS * i] = make_float2(0.f, 0.f);
    __syncthreads();

    // ---- scatter: z[j][h1[c]].re += s1*x1, z[j][h2[c]].im += s2*x2 ----
#pragma unroll
    for (int r = 0; r < 4; ++r) {
        const float4 a = v1[r], c4 = v2[r];
        const int   q1 = b1[r], q2 = b2[r];
        const float u1 = w1[r], u2 = w2[r];
        atomicAdd(&Z[0][q1].x, u1 * a.x);
        atomicAdd(&Z[1][q1].x, u1 * a.y);
        atomicAdd(&Z[2][q1].x, u1 * a.z);
        atomicAdd(&Z[3][q1].x, u1 * a.w);
        atomicAdd(&Z[0][q2].y, u2 * c4.x);
        atomicAdd(&Z[1][q2].y, u2 * c4.y);
        atomicAdd(&Z[2][q2].y, u2 * c4.z);
        atomicAdd(&Z[3][q2].y, u2 * c4.w);
    }
    __syncthreads();

    const int g = tid >> 5;       // position group 0..3 (one per 32 lanes)
    const int p = tid & 31;
    float2* zg = &Z[g][0];

    // forward FFT of z = p1 + i*p2  (wave-local, no block barriers)
    four_step<-1>(zg, p);

    // Hermitian unpack + pointwise product; all touched elements are written
    // by lanes of the same wave in the same iteration -> wave-ordered.
#pragma unroll
    for (int m = 0; m < 16; ++m) {
        const int k = p + (m << 5);
        if (k == 0) {
            float2 z0 = zg[0];
            float2 z5 = zg[512];
            zg[0]   = make_float2(z0.x * z0.y, 0.f);
            zg[512] = make_float2(z5.x * z5.y, 0.f);
        } else {
            float2 za = zg[k];
            float2 zb = zg[1024 - k];
            float2 F1 = make_float2(0.5f * (za.x + zb.x), 0.5f * (za.y - zb.y));
            float2 F2 = make_float2(0.5f * (za.y + zb.y), -0.5f * (za.x - zb.x));
            float2 G  = cmul(F1, F2);
            zg[k]        = G;
            zg[1024 - k] = make_float2(G.x, -G.y);
        }
    }
    __builtin_amdgcn_wave_barrier();

    // inverse FFT (unnormalized); real part / 1024 is the conv result
    four_step<1>(zg, p);
    __syncthreads();

    // ---- store: float4 along n for each o ----
    const int obase = b * (O_DIM * HW) + n0;
#pragma unroll
    for (int r = 0; r < O_DIM / NTHREADS; ++r) {
        const int o = tid + NTHREADS * r;
        float4 res;
        res.x = Z[0][o].x * (1.f / 1024.f);
        res.y = Z[1][o].x * (1.f / 1024.f);
        res.z = Z[2][o].x * (1.f / 1024.f);
        res.w = Z[3][o].x * (1.f / 1024.f);
        *reinterpret_cast<float4*>(out + obase + o * HW) = res;
    }
}

extern "C" void kernel_launch(void* const* d_in, const int* in_sizes, int n_in,
                              void* d_out, int out_size, void* d_ws, size_t ws_size,
                              hipStream_t stream) {
    const float* x1  = (const float*)d_in[0];
    const float* x2  = (const float*)d_in[1];
    const float* sk1 = (const float*)d_in[2];
    const float* sk2 = (const float*)d_in[3];
    float* out = (float*)d_out;

    int*   h = (int*)d_ws;                         // [0..511]=h1, [512..1023]=h2
    float* s = (float*)((char*)d_ws + 4096);       // [0..511]=s1, [512..1023]=s2

    hipLaunchKernelGGL(extract_sketch, dim3(O_DIM), dim3(256), 0, stream,
                       sk1, sk2, h, s);
    hipLaunchKernelGGL(cbp_main, dim3(B_DIM * NTILES), dim3(NTHREADS), 0, stream,
                       x1, x2, h, h + C_DIM, s, s + C_DIM, out);
}

// Round 4
// 361.488 us; speedup vs baseline: 1.1610x; 1.0010x over previous
//
#include <hip/hip_runtime.h>

#define O_DIM   1024
#define C_DIM   512
#define HW      784
#define B_DIM   32
#define T_POS   8                // 8 consecutive n per wg => 32B-sector-clean HBM
#define NTILES  (HW / T_POS)     // 98
#define NTHREADS 256

__device__ __forceinline__ float2 cmul(float2 a, float2 b) {
    return make_float2(a.x * b.x - a.y * b.y, a.x * b.y + a.y * b.x);
}

// 32-point in-register DIF FFT. SGN=-1 forward, +1 inverse (no scaling).
// Input natural order; output y[i] = X[rev5(i)].
template<int SGN>
__device__ __forceinline__ void fft32(float2 y[32]) {
    static constexpr float C32[16] = {
        1.f, 0.98078528f, 0.92387953f, 0.83146961f,
        0.70710678f, 0.55557023f, 0.38268343f, 0.19509032f,
        0.f, -0.19509032f, -0.38268343f, -0.55557023f,
        -0.70710678f, -0.83146961f, -0.92387953f, -0.98078528f};
    static constexpr float S32[16] = {
        0.f, 0.19509032f, 0.38268343f, 0.55557023f,
        0.70710678f, 0.83146961f, 0.92387953f, 0.98078528f,
        1.f, 0.98078528f, 0.92387953f, 0.83146961f,
        0.70710678f, 0.55557023f, 0.38268343f, 0.19509032f};
#pragma unroll
    for (int s = 0; s < 5; ++s) {
        const int L = 32 >> s;
        const int h = 16 >> s;
#pragma unroll
        for (int u = 0; u < 16; ++u) {
            const int blk = u >> (4 - s);
            const int t   = u & (h - 1);
            const int i   = blk * L + t;
            const int m   = t << s;            // twiddle index: W32^m
            float2 a = y[i], b = y[i + h];
            y[i] = make_float2(a.x + b.x, a.y + b.y);
            float2 d = make_float2(a.x - b.x, a.y - b.y);
            if (m == 0) {
                y[i + h] = d;
            } else if (m == 8) {
                y[i + h] = (SGN < 0) ? make_float2(d.y, -d.x)
                                     : make_float2(-d.y, d.x);
            } else {
                float2 w = make_float2(C32[m], (SGN < 0) ? -S32[m] : S32[m]);
                y[i + h] = cmul(d, w);
            }
        }
    }
}

__device__ const int REV5[32] = {
    0,16,8,24,4,20,12,28,2,18,10,26,6,22,14,30,
    1,17,9,25,5,21,13,29,3,19,11,27,7,23,15,31};

// Four-step 1024-pt FFT steps A..D over zg[0..1023]; one 32-lane group (inside
// ONE wave) owns this row -> same-wave DS ordering, no block barriers needed.
// On return y[rev5(k1)] holds X[p + 32*k1]; caller does the epilogue.
template<int SGN>
__device__ __forceinline__ void four_step_core(float2* zg, int p, float2 y[32]) {
#pragma unroll
    for (int n2 = 0; n2 < 32; ++n2)
        y[n2] = zg[p + 32 * n2];
    __builtin_amdgcn_wave_barrier();
    fft32<SGN>(y);                 // A[p][k2] at y[rev5(k2)]
    float sv, cv;
    __sincosf((float)SGN * 6.283185307179586f * (float)p * (1.f / 1024.f), &sv, &cv);
    const float2 stw = make_float2(cv, sv);
    float2 w = make_float2(1.f, 0.f);
#pragma unroll
    for (int k2 = 0; k2 < 32; ++k2) {
        float2 val = y[REV5[k2]];
        if (k2 > 0) val = cmul(val, w);
        zg[k2 * 32 + ((p + k2) & 31)] = val;   // row k2, swizzled col p
        w = cmul(w, stw);
    }
    __builtin_amdgcn_wave_barrier();
#pragma unroll
    for (int n1 = 0; n1 < 32; ++n1)
        y[n1] = zg[p * 32 + ((n1 + p) & 31)];
    __builtin_amdgcn_wave_barrier();
    fft32<SGN>(y);                 // B[p][k1] at y[rev5(k1)]
}

// One block per output row o; lanes sweep c coalesced. Each column c has
// exactly one nonzero across o, so the winning thread writes without races.
__global__ void extract_sketch(const float* __restrict__ sk1,
                               const float* __restrict__ sk2,
                               int* __restrict__ h, float* __restrict__ s) {
    const int o = blockIdx.x;                 // 0..1023
    for (int c = threadIdx.x; c < C_DIM; c += blockDim.x) {
        float v1 = sk1[o * C_DIM + c];
        if (v1 != 0.f) { h[c] = o; s[c] = v1; }
        float v2 = sk2[o * C_DIM + c];
        if (v2 != 0.f) { h[C_DIM + c] = o; s[C_DIM + c] = v2; }
    }
}

__global__ __launch_bounds__(NTHREADS, 2)
void cbp_main(const float* __restrict__ x1, const float* __restrict__ x2,
              const int* __restrict__ h1, const int* __restrict__ h2,
              const float* __restrict__ s1, const float* __restrict__ s2,
              float* __restrict__ out) {
    // 64 KB: Z = [8][1024] complex for scatter+FFT; after the FFTs die,
    // the same space is reused as R = [1024][10] floats (pad 10 -> 2-way
    // bank aliasing only, 8B-aligned rows) for the output transpose.
    __shared__ float4 LBUF[4096];
    float2 (*Z)[O_DIM] = reinterpret_cast<float2(*)[O_DIM]>(LBUF);
    float*  R = reinterpret_cast<float*>(LBUF);

    const int tid  = threadIdx.x;
    const int b    = blockIdx.x / NTILES;
    const int tile = blockIdx.x % NTILES;
    const int n0   = tile * T_POS;

    // ---- prefetch x-tile (two channel rows per thread, 32 B each) ----
    const int c0 = tid;
    const int c1 = tid + NTHREADS;
    const int xoff = b * (C_DIM * HW) + n0;
    const float4* p10 = (const float4*)(x1 + xoff + c0 * HW);
    const float4* p11 = (const float4*)(x1 + xoff + c1 * HW);
    const float4* p20 = (const float4*)(x2 + xoff + c0 * HW);
    const float4* p21 = (const float4*)(x2 + xoff + c1 * HW);
    float4 a0 = p10[0], a1 = p10[1];   // x1 row c0, n0..n0+7
    float4 b0 = p11[0], b1 = p11[1];   // x1 row c1
    float4 d0 = p20[0], d1 = p20[1];   // x2 row c0
    float4 e0 = p21[0], e1 = p21[1];   // x2 row c1
    const int   q10 = h1[c0], q11 = h1[c1], q20 = h2[c0], q21 = h2[c1];
    const float w10 = s1[c0], w11 = s1[c1], w20 = s2[c0], w21 = s2[c1];

    // ---- zero LDS (hides the global-load latency) ----
#pragma unroll
    for (int i = 0; i < 4096 / NTHREADS; ++i)
        LBUF[tid + NTHREADS * i] = make_float4(0.f, 0.f, 0.f, 0.f);
    __syncthreads();

    // ---- scatter: Z[pos][h1[c]].x += s1*x1, Z[pos][h2[c]].y += s2*x2 ----
    {
        float v[8];
        v[0]=a0.x; v[1]=a0.y; v[2]=a0.z; v[3]=a0.w;
        v[4]=a1.x; v[5]=a1.y; v[6]=a1.z; v[7]=a1.w;
#pragma unroll
        for (int j = 0; j < 8; ++j) atomicAdd(&Z[j][q10].x, w10 * v[j]);
        v[0]=b0.x; v[1]=b0.y; v[2]=b0.z; v[3]=b0.w;
        v[4]=b1.x; v[5]=b1.y; v[6]=b1.z; v[7]=b1.w;
#pragma unroll
        for (int j = 0; j < 8; ++j) atomicAdd(&Z[j][q11].x, w11 * v[j]);
        v[0]=d0.x; v[1]=d0.y; v[2]=d0.z; v[3]=d0.w;
        v[4]=d1.x; v[5]=d1.y; v[6]=d1.z; v[7]=d1.w;
#pragma unroll
        for (int j = 0; j < 8; ++j) atomicAdd(&Z[j][q20].y, w20 * v[j]);
        v[0]=e0.x; v[1]=e0.y; v[2]=e0.z; v[3]=e0.w;
        v[4]=e1.x; v[5]=e1.y; v[6]=e1.z; v[7]=e1.w;
#pragma unroll
        for (int j = 0; j < 8; ++j) atomicAdd(&Z[j][q21].y, w21 * v[j]);
    }
    __syncthreads();

    const int g = tid >> 5;       // position group 0..7 (one per 32 lanes)
    const int p = tid & 31;
    float2* zg = &Z[g][0];
    float2 y[32];

    // ---- forward FFT of z = p1 + i*p2 (wave-local) ----
    four_step_core<-1>(zg, p, y);
#pragma unroll
    for (int k1 = 0; k1 < 32; ++k1)        // natural-order writeback
        zg[p + 32 * k1] = y[REV5[k1]];
    __builtin_amdgcn_wave_barrier();

    // ---- Hermitian unpack + pointwise product (wave-local) ----
#pragma unroll
    for (int m = 0; m < 16; ++m) {
        const int k = p + (m << 5);
        if (k == 0) {
            float2 z0 = zg[0];
            float2 z5 = zg[512];
            zg[0]   = make_float2(z0.x * z0.y, 0.f);
            zg[512] = make_float2(z5.x * z5.y, 0.f);
        } else {
            float2 za = zg[k];
            float2 zb = zg[1024 - k];
            float2 F1 = make_float2(0.5f * (za.x + zb.x), 0.5f * (za.y - zb.y));
            float2 F2 = make_float2(0.5f * (za.y + zb.y), -0.5f * (za.x - zb.x));
            float2 G  = cmul(F1, F2);
            zg[k]        = G;
            zg[1024 - k] = make_float2(G.x, -G.y);
        }
    }
    __builtin_amdgcn_wave_barrier();

    // ---- inverse FFT; results stay in registers ----
    four_step_core<1>(zg, p, y);
    __syncthreads();              // all groups done with Z before R overlay

    // ---- stage transpose: R[o][g] = conv[pos g][bucket o] ----
#pragma unroll
    for (int k1 = 0; k1 < 32; ++k1)
        R[(p + 32 * k1) * 10 + g] = y[REV5[k1]].x * (1.f / 1024.f);
    __syncthreads();

    // ---- store: 32 B (8 consecutive n) per o, sector-clean ----
    const int obase = b * (O_DIM * HW) + n0;
#pragma unroll
    for (int r = 0; r < O_DIM / NTHREADS; ++r) {
        const int o = tid + NTHREADS * r;
        const float* rp = &R[o * 10];
        float4 v0 = make_float4(rp[0], rp[1], rp[2], rp[3]);
        float4 v1 = make_float4(rp[4], rp[5], rp[6], rp[7]);
        float4* dst = (float4*)(out + obase + o * HW);
        dst[0] = v0;
        dst[1] = v1;
    }
}

extern "C" void kernel_launch(void* const* d_in, const int* in_sizes, int n_in,
                              void* d_out, int out_size, void* d_ws, size_t ws_size,
                              hipStream_t stream) {
    const float* x1  = (const float*)d_in[0];
    const float* x2  = (const float*)d_in[1];
    const float* sk1 = (const float*)d_in[2];
    const float* sk2 = (const float*)d_in[3];
    float* out = (float*)d_out;

    int*   h = (int*)d_ws;                         // [0..511]=h1, [512..1023]=h2
    float* s = (float*)((char*)d_ws + 4096);       // [0..511]=s1, [512..1023]=s2

    hipLaunchKernelGGL(extract_sketch, dim3(O_DIM), dim3(256), 0, stream,
                       sk1, sk2, h, s);
    hipLaunchKernelGGL(cbp_main, dim3(B_DIM * NTILES), dim3(NTHREADS), 0, stream,
                       x1, x2, h, h + C_DIM, s, s + C_DIM, out);
}